// Round 17
// baseline (347.057 us; speedup 1.0000x reference)
//
#include <hip/hip_runtime.h>

#define NB 16    // N*G
#define CD 64    // C == Cv
#define HD 2048  // H

typedef unsigned short u16;
typedef __attribute__((ext_vector_type(8))) short s16x8;  // 8 bf16 (4 VGPRs)
typedef __attribute__((ext_vector_type(4))) float f32x4;  // MFMA C/D

__device__ __forceinline__ u16 f2bf(float x){
    unsigned u = __float_as_uint(x);
    u += 0x7FFFu + ((u >> 16) & 1u);   // RNE
    return (u16)(u >> 16);
}
__device__ __forceinline__ float bf2f(u16 h){ return __uint_as_float(((unsigned)h) << 16); }
__device__ __forceinline__ void split2(float x, u16& h, u16& l){
    h = f2bf(x); l = f2bf(x - bf2f(h));   // x - hi is exact in fp32
}
union Frag { uint4 q; s16x8 s; };
__device__ __forceinline__ s16x8 ld8(const u16* p){ Frag f; f.q = *(const uint4*)p; return f.s; }
__device__ __forceinline__ f32x4 mfma16(s16x8 a, s16x8 b, f32x4 c){
    return __builtin_amdgcn_mfma_f32_16x16x32_bf16(a, b, c, 0, 0, 0);
}
// hi/lo A against single-plane B (B pre-rounded to bf16 consistently with its sum)
__device__ __forceinline__ f32x4 mm2(s16x8 ah, s16x8 al, s16x8 bh, f32x4 c){
    c = mfma16(ah, bh, c);
    c = mfma16(al, bh, c);
    return c;
}
__device__ __forceinline__ f32x4 z4(){ f32x4 v = {0.f,0.f,0.f,0.f}; return v; }

// XCD-aware swizzle (r10). All blocks on one XCD share bg in {2*xcd, 2*xcd+1}.
__device__ __forceinline__ void xcd_map(int& bg, int& tile){
    int lb = blockIdx.y*32 + blockIdx.x;
    int xcd = lb & 7, t = lb >> 3;
    bg = 2*xcd + (t >> 5);
    tile = t & 31;
}

// ---------------- prep kernels ----------------

// hi+lo planes (mu only -- k_final phase B keeps fp32-emulated mu)
__global__ void k_convert(const float* __restrict__ src, u16* __restrict__ dh,
                          u16* __restrict__ dl, int n4)
{
    int idx = blockIdx.x*256 + threadIdx.x;
    if (idx >= n4) return;
    float4 v = ((const float4*)src)[idx];
    ushort4 h, l;
    split2(v.x, h.x, l.x); split2(v.y, h.y, l.y);
    split2(v.z, h.z, l.z); split2(v.w, h.w, l.w);
    ((ushort4*)dh)[idx] = h;
    ((ushort4*)dl)[idx] = l;
}

// fused q prep: one read of q -> qN (hi, natural) + qT (hi, transposed)
__global__ void k_prep_q(const float* __restrict__ src, u16* __restrict__ dT,
                         u16* __restrict__ dN)
{
    int bg = blockIdx.y, h0 = blockIdx.x*128, tid = threadIdx.x;
    __shared__ float ft[CD][132];
    #pragma unroll
    for (int k=0;k<8;k++){
        int flat = tid + 256*k;
        int c = flat >> 5, p = (flat & 31)*4;
        size_t goff = ((size_t)bg*CD + c)*HD + h0 + p;
        float4 v = *(const float4*)(src + goff);
        *(float4*)&ft[c][p] = v;
        ushort4 h;
        h.x = f2bf(v.x); h.y = f2bf(v.y); h.z = f2bf(v.z); h.w = f2bf(v.w);
        *(ushort4*)(dN + goff) = h;
    }
    __syncthreads();
    int hl = tid >> 1, c0 = (tid & 1)*32;
    union { u16 u[32]; uint4 q[4]; } oh;
    #pragma unroll
    for (int m=0;m<32;m++)
        oh.u[m] = f2bf(ft[c0+m][hl]);
    size_t base = ((size_t)bg*HD + h0 + hl)*CD + c0;
    #pragma unroll
    for (int t=0;t<4;t++)
        *((uint4*)(dT + base) + t) = oh.q[t];
}

// hi-only transpose (z^T)
__global__ void k_transpose1(const float* __restrict__ src, u16* __restrict__ dh)
{
    int bg = blockIdx.y, h0 = blockIdx.x*128, tid = threadIdx.x;
    __shared__ float ft[CD][132];
    #pragma unroll
    for (int k=0;k<8;k++){
        int flat = tid + 256*k;
        int c = flat >> 5, p = (flat & 31)*4;
        *(float4*)&ft[c][p] = *(const float4*)(src + ((size_t)bg*CD + c)*HD + h0 + p);
    }
    __syncthreads();
    int hl = tid >> 1, c0 = (tid & 1)*32;
    union { u16 u[32]; uint4 q[4]; } oh;
    #pragma unroll
    for (int m=0;m<32;m++)
        oh.u[m] = f2bf(ft[c0+m][hl]);
    size_t base = ((size_t)bg*HD + h0 + hl)*CD + c0;
    #pragma unroll
    for (int t=0;t<4;t++)
        *((uint4*)(dh + base) + t) = oh.q[t];
}

__global__ void k_bias(const float* __restrict__ mu, const float* __restrict__ beta,
                       float* __restrict__ bias)
{
    int bg = blockIdx.y;
    int j  = blockIdx.x*256 + threadIdx.x;
    const float* m = mu + (size_t)bg*CD*HD + j;
    float s = 0.f;
    #pragma unroll
    for (int c=0;c<CD;c++){ float v = m[(size_t)c*HD]; s = fmaf(v, v, s); }
    bias[(size_t)bg*HD + j] = 0.5f * beta[0] * s;
}

// ---------------- main MFMA kernels ----------------
// Precision scheme (r12-r16, absmax pinned at 2^-11): all softmax logits hi-only
// bf16, each softmax exactly normalized against its own rounded weights. Only
// k_final's value matmul (e x mu) keeps hi/lo fp32 emulation.
// r17: cross-step software pipeline (named register sets, prefetch next step's
// operands under the w/e-block + barrier + phase B) -- viable now that VGPR=112
// leaves headroom the allocator lacked in r3/r5/r9.

// r[i] = sum_j exp(a*S~+bias_j), S~ = hi-only bf16 S. (unchanged from r16)
__global__ __launch_bounds__(256,2) void k_rowsum(
    const u16* __restrict__ qTh,
    const u16* __restrict__ zTh,
    const float* __restrict__ bias, const float* __restrict__ alpha,
    float* __restrict__ r)
{
    int bg, itile; xcd_map(bg, itile);
    const int i0 = itile*64;
    const int tid = threadIdx.x, wave = tid>>6, lane = tid&63, ln = lane&15, quad = lane>>4;
    const int jw = wave*32;
    const float a = alpha[0];
    __shared__ float rpart[4][64];

    s16x8 Ah[4][2];               // resident q^T frags (hi only): rows i0..i0+63
    #pragma unroll
    for (int mt=0;mt<4;mt++)
        #pragma unroll
        for (int ks=0;ks<2;ks++){
            size_t off = ((size_t)bg*HD + i0 + mt*16 + ln)*CD + ks*32 + quad*8;
            Ah[mt][ks] = ld8(qTh + off);
        }
    float racc[16];
    #pragma unroll
    for (int k=0;k<16;k++) racc[k] = 0.f;
    const float* bb = bias + (size_t)bg*HD;

    s16x8 B0h[2][2], B1h[2][2];
    float bj0[2], bj1[2];

    // prologue: tile 0
    #pragma unroll
    for (int nt=0;nt<2;nt++){
        #pragma unroll
        for (int ks=0;ks<2;ks++){
            size_t off = ((size_t)bg*HD + jw + nt*16 + ln)*CD + ks*32 + quad*8;
            B0h[nt][ks] = ld8(zTh + off);
        }
        bj0[nt] = bb[jw + nt*16 + ln];
    }

    for (int j0=0;j0<HD;j0+=256){
        #pragma unroll
        for (int nt=0;nt<2;nt++){
            #pragma unroll
            for (int ks=0;ks<2;ks++){
                size_t off = ((size_t)bg*HD + j0+128 + jw + nt*16 + ln)*CD + ks*32 + quad*8;
                B1h[nt][ks] = ld8(zTh + off);
            }
            bj1[nt] = bb[j0+128 + jw + nt*16 + ln];
        }
        __builtin_amdgcn_sched_barrier(0);
        {
            f32x4 acc[4][2];
            #pragma unroll
            for (int mt=0;mt<4;mt++){ acc[mt][0]=z4(); acc[mt][1]=z4(); }
            __builtin_amdgcn_s_setprio(1);
            #pragma unroll
            for (int ks=0;ks<2;ks++)
                #pragma unroll
                for (int mt=0;mt<4;mt++)
                    #pragma unroll
                    for (int nt=0;nt<2;nt++)
                        acc[mt][nt] = mfma16(Ah[mt][ks], B0h[nt][ks], acc[mt][nt]);
            __builtin_amdgcn_s_setprio(0);
            #pragma unroll
            for (int mt=0;mt<4;mt++)
                #pragma unroll
                for (int nt=0;nt<2;nt++)
                    #pragma unroll
                    for (int rx=0;rx<4;rx++)
                        racc[mt*4+rx] += __expf(fmaf(a, acc[mt][nt][rx], bj0[nt]));
        }
        {
            int jn2 = (j0+256) & (HD-1);
            #pragma unroll
            for (int nt=0;nt<2;nt++){
                #pragma unroll
                for (int ks=0;ks<2;ks++){
                    size_t off = ((size_t)bg*HD + jn2 + jw + nt*16 + ln)*CD + ks*32 + quad*8;
                    B0h[nt][ks] = ld8(zTh + off);
                }
                bj0[nt] = bb[jn2 + jw + nt*16 + ln];
            }
        }
        __builtin_amdgcn_sched_barrier(0);
        {
            f32x4 acc[4][2];
            #pragma unroll
            for (int mt=0;mt<4;mt++){ acc[mt][0]=z4(); acc[mt][1]=z4(); }
            __builtin_amdgcn_s_setprio(1);
            #pragma unroll
            for (int ks=0;ks<2;ks++)
                #pragma unroll
                for (int mt=0;mt<4;mt++)
                    #pragma unroll
                    for (int nt=0;nt<2;nt++)
                        acc[mt][nt] = mfma16(Ah[mt][ks], B1h[nt][ks], acc[mt][nt]);
            __builtin_amdgcn_s_setprio(0);
            #pragma unroll
            for (int mt=0;mt<4;mt++)
                #pragma unroll
                for (int nt=0;nt<2;nt++)
                    #pragma unroll
                    for (int rx=0;rx<4;rx++)
                        racc[mt*4+rx] += __expf(fmaf(a, acc[mt][nt][rx], bj1[nt]));
        }
    }
    #pragma unroll
    for (int k=0;k<16;k++){
        float v = racc[k];
        v += __shfl_xor(v,1); v += __shfl_xor(v,2);
        v += __shfl_xor(v,4); v += __shfl_xor(v,8);
        racc[k] = v;
    }
    if (ln == 0){
        #pragma unroll
        for (int mt=0;mt<4;mt++)
            #pragma unroll
            for (int rx=0;rx<4;rx++)
                rpart[wave][mt*16 + quad*4 + rx] = racc[mt*4+rx];
    }
    __syncthreads();
    if (tid < 64)
        r[(size_t)bg*HD + i0 + tid] = rpart[0][tid]+rpart[1][tid]+rpart[2][tid]+rpart[3][tid];
}

// zeta update, 2-step pipelined: set0/set1 register sets; prefetch next step's
// q^T/qN/r under {w-block + barrier + phase B}.
__global__ __launch_bounds__(256,2) void k_update(
    const u16* __restrict__ qTh,
    u16* zTh,                                          // read then overwritten (own rows only)
    const u16* __restrict__ qNh,
    const float* __restrict__ bias, const float* __restrict__ alpha,
    const float* __restrict__ r)
{
    int bg, jtile; xcd_map(bg, jtile);
    const int j0 = jtile*64;
    const int tid = threadIdx.x, wave = tid>>6, lane = tid&63, ln = lane&15, quad = lane>>4;
    const int cm = (wave&1)*32, jn = (wave>>1)*32;
    const float a = alpha[0];
    __shared__ u16 wl[2][64*128];                     // double-buffered w^T [j][i], swizzled
    __shared__ float denl[4][64];

    s16x8 Bh[4][2];               // resident z^T frags (hi only): rows j0..j0+63
    #pragma unroll
    for (int nt=0;nt<4;nt++)
        #pragma unroll
        for (int ks=0;ks<2;ks++){
            size_t off = ((size_t)bg*HD + j0 + nt*16 + ln)*CD + ks*32 + quad*8;
            Bh[nt][ks] = ld8(zTh + off);
        }
    float bj[4];
    #pragma unroll
    for (int nt=0;nt<4;nt++) bj[nt] = bias[(size_t)bg*HD + j0 + nt*16 + ln];

    f32x4 acc2[2][2] = {{z4(),z4()},{z4(),z4()}};
    float den[4] = {0.f,0.f,0.f,0.f};

    // pipeline register sets
    s16x8 Ah0[2][2], A2h0[4][2]; float ri0[8];
    s16x8 Ah1[2][2], A2h1[4][2]; float ri1[8];

    // prologue: load set0 for is=0
    #pragma unroll
    for (int ks=0;ks<2;ks++)
        #pragma unroll
        for (int mt=0;mt<2;mt++){
            size_t off = ((size_t)bg*HD + 0 + wave*32 + mt*16 + ln)*CD + ks*32 + quad*8;
            Ah0[mt][ks] = ld8(qTh + off);
        }
    #pragma unroll
    for (int ks2=0;ks2<4;ks2++)
        #pragma unroll
        for (int mtN=0;mtN<2;mtN++){
            size_t off = ((size_t)bg*CD + cm + mtN*16 + ln)*HD + 0 + ks2*32 + quad*8;
            A2h0[ks2][mtN] = ld8(qNh + off);
        }
    #pragma unroll
    for (int mt=0;mt<2;mt++){
        float4 rv = *(const float4*)&r[(size_t)bg*HD + 0 + wave*32 + mt*16 + quad*4];
        ri0[mt*4+0] = __builtin_amdgcn_rcpf(rv.x);
        ri0[mt*4+1] = __builtin_amdgcn_rcpf(rv.y);
        ri0[mt*4+2] = __builtin_amdgcn_rcpf(rv.z);
        ri0[mt*4+3] = __builtin_amdgcn_rcpf(rv.w);
    }

    for (int t=0; t<16; t+=2){
        const int is1 = (t+1)*128, is2 = (t+2)*128;

        // ======== EVEN step t: uses set0, LDS buf 0 ========
        {
            f32x4 acc1[2][4];
            #pragma unroll
            for (int mt=0;mt<2;mt++)
                #pragma unroll
                for (int nt=0;nt<4;nt++) acc1[mt][nt] = z4();
            __builtin_amdgcn_s_setprio(1);
            #pragma unroll
            for (int ks=0;ks<2;ks++)
                #pragma unroll
                for (int mt=0;mt<2;mt++)
                    #pragma unroll
                    for (int nt=0;nt<4;nt++)
                        acc1[mt][nt] = mfma16(Ah0[mt][ks], Bh[nt][ks], acc1[mt][nt]);
            __builtin_amdgcn_s_setprio(0);
            // ---- prefetch set1 @ is1 ----
            #pragma unroll
            for (int ks=0;ks<2;ks++)
                #pragma unroll
                for (int mt=0;mt<2;mt++){
                    size_t off = ((size_t)bg*HD + is1 + wave*32 + mt*16 + ln)*CD + ks*32 + quad*8;
                    Ah1[mt][ks] = ld8(qTh + off);
                }
            #pragma unroll
            for (int ks2=0;ks2<4;ks2++)
                #pragma unroll
                for (int mtN=0;mtN<2;mtN++){
                    size_t off = ((size_t)bg*CD + cm + mtN*16 + ln)*HD + is1 + ks2*32 + quad*8;
                    A2h1[ks2][mtN] = ld8(qNh + off);
                }
            #pragma unroll
            for (int mt=0;mt<2;mt++){
                float4 rv = *(const float4*)&r[(size_t)bg*HD + is1 + wave*32 + mt*16 + quad*4];
                ri1[mt*4+0] = __builtin_amdgcn_rcpf(rv.x);
                ri1[mt*4+1] = __builtin_amdgcn_rcpf(rv.y);
                ri1[mt*4+2] = __builtin_amdgcn_rcpf(rv.z);
                ri1[mt*4+3] = __builtin_amdgcn_rcpf(rv.w);
            }
            __builtin_amdgcn_sched_barrier(0);
            // ---- w compute + LDS write buf0 ----
            #pragma unroll
            for (int mt=0;mt<2;mt++)
                #pragma unroll
                for (int nt=0;nt<4;nt++){
                    u16 hh[4];
                    #pragma unroll
                    for (int rx=0;rx<4;rx++){
                        float w = __expf(fmaf(a, acc1[mt][nt][rx], bj[nt])) * ri0[mt*4+rx];
                        hh[rx] = f2bf(w);
                        den[nt] += bf2f(hh[rx]);
                    }
                    int row = nt*16 + ln;
                    int c4  = wave*32 + mt*16 + quad*4;
                    int off = (row<<7) + ((((c4>>3) ^ (row&15))<<3) | (c4&7));
                    *(ushort4*)&wl[0][off] = make_ushort4(hh[0],hh[1],hh[2],hh[3]);
                }
            __syncthreads();
            // ---- phase B buf0 (A2h0) ----
            __builtin_amdgcn_s_setprio(1);
            #pragma unroll
            for (int ks2=0;ks2<4;ks2++){
                s16x8 B2h[2];
                #pragma unroll
                for (int nt2=0;nt2<2;nt2++){
                    int jl = jn + nt2*16 + ln;
                    int ob = (jl<<7) + (((ks2*4+quad) ^ (jl&15))<<3);
                    B2h[nt2] = ld8(&wl[0][ob]);
                }
                #pragma unroll
                for (int mtN=0;mtN<2;mtN++)
                    #pragma unroll
                    for (int nt2=0;nt2<2;nt2++)
                        acc2[mtN][nt2] = mfma16(A2h0[ks2][mtN], B2h[nt2], acc2[mtN][nt2]);
            }
            __builtin_amdgcn_s_setprio(0);
        }

        // ======== ODD step t+1: uses set1, LDS buf 1 ========
        {
            f32x4 acc1[2][4];
            #pragma unroll
            for (int mt=0;mt<2;mt++)
                #pragma unroll
                for (int nt=0;nt<4;nt++) acc1[mt][nt] = z4();
            __builtin_amdgcn_s_setprio(1);
            #pragma unroll
            for (int ks=0;ks<2;ks++)
                #pragma unroll
                for (int mt=0;mt<2;mt++)
                    #pragma unroll
                    for (int nt=0;nt<4;nt++)
                        acc1[mt][nt] = mfma16(Ah1[mt][ks], Bh[nt][ks], acc1[mt][nt]);
            __builtin_amdgcn_s_setprio(0);
            // ---- prefetch set0 @ is2 (guard tail) ----
            if (t < 14){
                #pragma unroll
                for (int ks=0;ks<2;ks++)
                    #pragma unroll
                    for (int mt=0;mt<2;mt++){
                        size_t off = ((size_t)bg*HD + is2 + wave*32 + mt*16 + ln)*CD + ks*32 + quad*8;
                        Ah0[mt][ks] = ld8(qTh + off);
                    }
                #pragma unroll
                for (int ks2=0;ks2<4;ks2++)
                    #pragma unroll
                    for (int mtN=0;mtN<2;mtN++){
                        size_t off = ((size_t)bg*CD + cm + mtN*16 + ln)*HD + is2 + ks2*32 + quad*8;
                        A2h0[ks2][mtN] = ld8(qNh + off);
                    }
                #pragma unroll
                for (int mt=0;mt<2;mt++){
                    float4 rv = *(const float4*)&r[(size_t)bg*HD + is2 + wave*32 + mt*16 + quad*4];
                    ri0[mt*4+0] = __builtin_amdgcn_rcpf(rv.x);
                    ri0[mt*4+1] = __builtin_amdgcn_rcpf(rv.y);
                    ri0[mt*4+2] = __builtin_amdgcn_rcpf(rv.z);
                    ri0[mt*4+3] = __builtin_amdgcn_rcpf(rv.w);
                }
            }
            __builtin_amdgcn_sched_barrier(0);
            // ---- w compute + LDS write buf1 ----
            #pragma unroll
            for (int mt=0;mt<2;mt++)
                #pragma unroll
                for (int nt=0;nt<4;nt++){
                    u16 hh[4];
                    #pragma unroll
                    for (int rx=0;rx<4;rx++){
                        float w = __expf(fmaf(a, acc1[mt][nt][rx], bj[nt])) * ri1[mt*4+rx];
                        hh[rx] = f2bf(w);
                        den[nt] += bf2f(hh[rx]);
                    }
                    int row = nt*16 + ln;
                    int c4  = wave*32 + mt*16 + quad*4;
                    int off = (row<<7) + ((((c4>>3) ^ (row&15))<<3) | (c4&7));
                    *(ushort4*)&wl[1][off] = make_ushort4(hh[0],hh[1],hh[2],hh[3]);
                }
            __syncthreads();
            // ---- phase B buf1 (A2h1) ----
            __builtin_amdgcn_s_setprio(1);
            #pragma unroll
            for (int ks2=0;ks2<4;ks2++){
                s16x8 B2h[2];
                #pragma unroll
                for (int nt2=0;nt2<2;nt2++){
                    int jl = jn + nt2*16 + ln;
                    int ob = (jl<<7) + (((ks2*4+quad) ^ (jl&15))<<3);
                    B2h[nt2] = ld8(&wl[1][ob]);
                }
                #pragma unroll
                for (int mtN=0;mtN<2;mtN++)
                    #pragma unroll
                    for (int nt2=0;nt2<2;nt2++)
                        acc2[mtN][nt2] = mfma16(A2h1[ks2][mtN], B2h[nt2], acc2[mtN][nt2]);
            }
            __builtin_amdgcn_s_setprio(0);
        }
    }
    // denominator reduce: quads via shfl, waves via LDS
    #pragma unroll
    for (int nt=0;nt<4;nt++){
        float v = den[nt];
        v += __shfl_xor(v,16); v += __shfl_xor(v,32);
        if (quad == 0) denl[wave][nt*16 + ln] = v;
    }
    __syncthreads();
    #pragma unroll
    for (int nt2=0;nt2<2;nt2++){
        int jl = jn + nt2*16 + ln;
        float dinv = __builtin_amdgcn_rcpf(denl[0][jl]+denl[1][jl]+denl[2][jl]+denl[3][jl]);
        #pragma unroll
        for (int mtN=0;mtN<2;mtN++){
            u16 hh[4];
            #pragma unroll
            for (int rx=0;rx<4;rx++)
                hh[rx] = f2bf(acc2[mtN][nt2][rx] * dinv);
            size_t off = ((size_t)bg*HD + j0 + jl)*CD + cm + mtN*16 + quad*4;
            *(ushort4*)(zTh + off) = make_ushort4(hh[0],hh[1],hh[2],hh[3]);
        }
    }
}

// final, 2-step pipelined on z+bias (mu single-buffered: it already has
// phaseA+e-block cover). Phase B keeps hi/lo mu (mm2).
__global__ __launch_bounds__(256,2) void k_final(
    const u16* __restrict__ qTh,
    const u16* __restrict__ zTh,
    const u16* __restrict__ muh, const u16* __restrict__ mul_,
    const float* __restrict__ bias, const float* __restrict__ alpha,
    float* __restrict__ out)
{
    int bg, itile; xcd_map(bg, itile);
    const int i0 = itile*64;
    const int tid = threadIdx.x, wave = tid>>6, lane = tid&63, ln = lane&15, quad = lane>>4;
    const int cm = (wave&1)*32, in_ = (wave>>1)*32;
    const float a = alpha[0];
    __shared__ u16 el[2][64*128];                     // double-buffered e^T [i][j], swizzled
    __shared__ float rl2[4][64];

    s16x8 Bh[4][2];               // resident q^T frags (hi only): rows i0..i0+63 (n operand)
    #pragma unroll
    for (int nt=0;nt<4;nt++)
        #pragma unroll
        for (int ks=0;ks<2;ks++){
            size_t off = ((size_t)bg*HD + i0 + nt*16 + ln)*CD + ks*32 + quad*8;
            Bh[nt][ks] = ld8(qTh + off);
        }
    f32x4 acc2[2][2] = {{z4(),z4()},{z4(),z4()}};
    float racc[4] = {0.f,0.f,0.f,0.f};

    // pipeline sets (z + bias only)
    s16x8 Ah0[2][2], Ah1[2][2];
    float bj0[8], bj1[8];

    // prologue: set0 @ js=0
    #pragma unroll
    for (int ks=0;ks<2;ks++)
        #pragma unroll
        for (int mt=0;mt<2;mt++){
            size_t off = ((size_t)bg*HD + 0 + wave*32 + mt*16 + ln)*CD + ks*32 + quad*8;
            Ah0[mt][ks] = ld8(zTh + off);
        }
    #pragma unroll
    for (int mt=0;mt<2;mt++){
        float4 bv = *(const float4*)&bias[(size_t)bg*HD + 0 + wave*32 + mt*16 + quad*4];
        bj0[mt*4+0]=bv.x; bj0[mt*4+1]=bv.y; bj0[mt*4+2]=bv.z; bj0[mt*4+3]=bv.w;
    }

    for (int t=0; t<16; t+=2){
        const int js0 = t*128, js1 = js0+128, js2 = js0+256;

        // ======== EVEN step: set0, buf0 ========
        {
            // mu loads for this step (single-buffered; cover = phaseA + e-block + barrier)
            s16x8 A2h[4][2], A2l[4][2];
            #pragma unroll
            for (int ks2=0;ks2<4;ks2++)
                #pragma unroll
                for (int mtN=0;mtN<2;mtN++){
                    size_t off = ((size_t)bg*CD + cm + mtN*16 + ln)*HD + js0 + ks2*32 + quad*8;
                    A2h[ks2][mtN] = ld8(muh + off);
                    A2l[ks2][mtN] = ld8(mul_ + off);
                }
            f32x4 acc1[2][4];
            #pragma unroll
            for (int mt=0;mt<2;mt++)
                #pragma unroll
                for (int nt=0;nt<4;nt++) acc1[mt][nt] = z4();
            __builtin_amdgcn_s_setprio(1);
            #pragma unroll
            for (int ks=0;ks<2;ks++)
                #pragma unroll
                for (int mt=0;mt<2;mt++)
                    #pragma unroll
                    for (int nt=0;nt<4;nt++)
                        acc1[mt][nt] = mfma16(Ah0[mt][ks], Bh[nt][ks], acc1[mt][nt]);
            __builtin_amdgcn_s_setprio(0);
            // ---- prefetch set1 @ js1 ----
            #pragma unroll
            for (int ks=0;ks<2;ks++)
                #pragma unroll
                for (int mt=0;mt<2;mt++){
                    size_t off = ((size_t)bg*HD + js1 + wave*32 + mt*16 + ln)*CD + ks*32 + quad*8;
                    Ah1[mt][ks] = ld8(zTh + off);
                }
            #pragma unroll
            for (int mt=0;mt<2;mt++){
                float4 bv = *(const float4*)&bias[(size_t)bg*HD + js1 + wave*32 + mt*16 + quad*4];
                bj1[mt*4+0]=bv.x; bj1[mt*4+1]=bv.y; bj1[mt*4+2]=bv.z; bj1[mt*4+3]=bv.w;
            }
            __builtin_amdgcn_sched_barrier(0);
            // ---- e compute + LDS write buf0 ----
            #pragma unroll
            for (int mt=0;mt<2;mt++)
                #pragma unroll
                for (int nt=0;nt<4;nt++){
                    u16 hh[4];
                    #pragma unroll
                    for (int rx=0;rx<4;rx++){
                        float e = __expf(fmaf(a, acc1[mt][nt][rx], bj0[mt*4+rx]));
                        hh[rx] = f2bf(e);
                        racc[nt] += bf2f(hh[rx]);
                    }
                    int row = nt*16 + ln;
                    int c4  = wave*32 + mt*16 + quad*4;
                    int off = (row<<7) + ((((c4>>3) ^ (row&15))<<3) | (c4&7));
                    *(ushort4*)&el[0][off] = make_ushort4(hh[0],hh[1],hh[2],hh[3]);
                }
            __syncthreads();
            // ---- phase B buf0 ----
            __builtin_amdgcn_s_setprio(1);
            #pragma unroll
            for (int ks2=0;ks2<4;ks2++){
                s16x8 B2h[2];
                #pragma unroll
                for (int nt2=0;nt2<2;nt2++){
                    int il = in_ + nt2*16 + ln;
                    int ob = (il<<7) + (((ks2*4+quad) ^ (il&15))<<3);
                    B2h[nt2] = ld8(&el[0][ob]);
                }
                #pragma unroll
                for (int mtN=0;mtN<2;mtN++)
                    #pragma unroll
                    for (int nt2=0;nt2<2;nt2++)
                        acc2[mtN][nt2] = mm2(A2h[ks2][mtN], A2l[ks2][mtN], B2h[nt2], acc2[mtN][nt2]);
            }
            __builtin_amdgcn_s_setprio(0);
        }

        // ======== ODD step: set1, buf1 ========
        {
            s16x8 A2h[4][2], A2l[4][2];
            #pragma unroll
            for (int ks2=0;ks2<4;ks2++)
                #pragma unroll
                for (int mtN=0;mtN<2;mtN++){
                    size_t off = ((size_t)bg*CD + cm + mtN*16 + ln)*HD + js1 + ks2*32 + quad*8;
                    A2h[ks2][mtN] = ld8(muh + off);
                    A2l[ks2][mtN] = ld8(mul_ + off);
                }
            f32x4 acc1[2][4];
            #pragma unroll
            for (int mt=0;mt<2;mt++)
                #pragma unroll
                for (int nt=0;nt<4;nt++) acc1[mt][nt] = z4();
            __builtin_amdgcn_s_setprio(1);
            #pragma unroll
            for (int ks=0;ks<2;ks++)
                #pragma unroll
                for (int mt=0;mt<2;mt++)
                    #pragma unroll
                    for (int nt=0;nt<4;nt++)
                        acc1[mt][nt] = mfma16(Ah1[mt][ks], Bh[nt][ks], acc1[mt][nt]);
            __builtin_amdgcn_s_setprio(0);
            // ---- prefetch set0 @ js2 (guard tail) ----
            if (t < 14){
                #pragma unroll
                for (int ks=0;ks<2;ks++)
                    #pragma unroll
                    for (int mt=0;mt<2;mt++){
                        size_t off = ((size_t)bg*HD + js2 + wave*32 + mt*16 + ln)*CD + ks*32 + quad*8;
                        Ah0[mt][ks] = ld8(zTh + off);
                    }
                #pragma unroll
                for (int mt=0;mt<2;mt++){
                    float4 bv = *(const float4*)&bias[(size_t)bg*HD + js2 + wave*32 + mt*16 + quad*4];
                    bj0[mt*4+0]=bv.x; bj0[mt*4+1]=bv.y; bj0[mt*4+2]=bv.z; bj0[mt*4+3]=bv.w;
                }
            }
            __builtin_amdgcn_sched_barrier(0);
            // ---- e compute + LDS write buf1 ----
            #pragma unroll
            for (int mt=0;mt<2;mt++)
                #pragma unroll
                for (int nt=0;nt<4;nt++){
                    u16 hh[4];
                    #pragma unroll
                    for (int rx=0;rx<4;rx++){
                        float e = __expf(fmaf(a, acc1[mt][nt][rx], bj1[mt*4+rx]));
                        hh[rx] = f2bf(e);
                        racc[nt] += bf2f(hh[rx]);
                    }
                    int row = nt*16 + ln;
                    int c4  = wave*32 + mt*16 + quad*4;
                    int off = (row<<7) + ((((c4>>3) ^ (row&15))<<3) | (c4&7));
                    *(ushort4*)&el[1][off] = make_ushort4(hh[0],hh[1],hh[2],hh[3]);
                }
            __syncthreads();
            // ---- phase B buf1 ----
            __builtin_amdgcn_s_setprio(1);
            #pragma unroll
            for (int ks2=0;ks2<4;ks2++){
                s16x8 B2h[2];
                #pragma unroll
                for (int nt2=0;nt2<2;nt2++){
                    int il = in_ + nt2*16 + ln;
                    int ob = (il<<7) + (((ks2*4+quad) ^ (il&15))<<3);
                    B2h[nt2] = ld8(&el[1][ob]);
                }
                #pragma unroll
                for (int mtN=0;mtN<2;mtN++)
                    #pragma unroll
                    for (int nt2=0;nt2<2;nt2++)
                        acc2[mtN][nt2] = mm2(A2h[ks2][mtN], A2l[ks2][mtN], B2h[nt2], acc2[mtN][nt2]);
            }
            __builtin_amdgcn_s_setprio(0);
        }
    }
    #pragma unroll
    for (int nt=0;nt<4;nt++){
        float v = racc[nt];
        v += __shfl_xor(v,16); v += __shfl_xor(v,32);
        if (quad == 0) rl2[wave][nt*16 + ln] = v;
    }
    __syncthreads();
    #pragma unroll
    for (int nt2=0;nt2<2;nt2++){
        int il = in_ + nt2*16 + ln;
        float rinv = __builtin_amdgcn_rcpf(rl2[0][il]+rl2[1][il]+rl2[2][il]+rl2[3][il]);
        #pragma unroll
        for (int mtN=0;mtN<2;mtN++)
            #pragma unroll
            for (int rx=0;rx<4;rx++)
                out[((size_t)bg*CD + cm + mtN*16 + quad*4 + rx)*HD + i0 + il]
                    = acc2[mtN][nt2][rx] * rinv;
    }
}

extern "C" void kernel_launch(void* const* d_in, const int* in_sizes, int n_in,
                              void* d_out, int out_size, void* d_ws, size_t ws_size,
                              hipStream_t stream)
{
    (void)in_sizes; (void)n_in; (void)out_size; (void)ws_size;
    const float* q     = (const float*)d_in[0];
    const float* zeta  = (const float*)d_in[1];
    const float* alpha = (const float*)d_in[2];
    const float* mu    = (const float*)d_in[3];
    const float* beta  = (const float*)d_in[4];
    float* out = (float*)d_out;

    const size_t SZ = (size_t)NB*HD*CD;   // elements per tensor
    u16* qTh = (u16*)d_ws;
    u16* zTh = qTh + 1*SZ;
    u16* qNh = qTh + 2*SZ;
    u16* muh = qTh + 3*SZ;
    u16* mul_= qTh + 4*SZ;
    float* bias = (float*)(qTh + 5*SZ);
    float* r    = bias + (size_t)NB*HD;

    dim3 blk(256,1,1);
    int n4 = (int)(SZ/4);
    k_prep_q   <<<dim3(HD/128, NB), blk, 0, stream>>>(q, qTh, qNh);
    k_convert  <<<dim3(n4/256), blk, 0, stream>>>(mu, muh, mul_, n4);
    k_transpose1<<<dim3(HD/128, NB), blk, 0, stream>>>(zeta, zTh);
    k_bias     <<<dim3(HD/256, NB), blk, 0, stream>>>(mu, beta, bias);

    k_rowsum<<<dim3(HD/64, NB), blk, 0, stream>>>(qTh,zTh,bias,alpha,r);
    k_update<<<dim3(HD/64, NB), blk, 0, stream>>>(qTh,zTh,qNh,bias,alpha,r);
    k_rowsum<<<dim3(HD/64, NB), blk, 0, stream>>>(qTh,zTh,bias,alpha,r);
    k_update<<<dim3(HD/64, NB), blk, 0, stream>>>(qTh,zTh,qNh,bias,alpha,r);
    k_final <<<dim3(HD/64, NB), blk, 0, stream>>>(qTh,zTh,muh,mul_,bias,alpha,out);
}

// Round 18
// 332.825 us; speedup vs baseline: 1.0428x; 1.0428x over previous
//
#include <hip/hip_runtime.h>

#define NB 16    // N*G
#define CD 64    // C == Cv
#define HD 2048  // H

typedef unsigned short u16;
typedef __attribute__((ext_vector_type(8))) short s16x8;  // 8 bf16 (4 VGPRs)
typedef __attribute__((ext_vector_type(4))) float f32x4;  // MFMA C/D

__device__ __forceinline__ u16 f2bf(float x){
    unsigned u = __float_as_uint(x);
    u += 0x7FFFu + ((u >> 16) & 1u);   // RNE
    return (u16)(u >> 16);
}
__device__ __forceinline__ float bf2f(u16 h){ return __uint_as_float(((unsigned)h) << 16); }
__device__ __forceinline__ void split2(float x, u16& h, u16& l){
    h = f2bf(x); l = f2bf(x - bf2f(h));   // x - hi is exact in fp32
}
union Frag { uint4 q; s16x8 s; };
__device__ __forceinline__ s16x8 ld8(const u16* p){ Frag f; f.q = *(const uint4*)p; return f.s; }
__device__ __forceinline__ f32x4 mfma16(s16x8 a, s16x8 b, f32x4 c){
    return __builtin_amdgcn_mfma_f32_16x16x32_bf16(a, b, c, 0, 0, 0);
}
// hi/lo A against single-plane B (B pre-rounded to bf16 consistently with its sum)
__device__ __forceinline__ f32x4 mm2(s16x8 ah, s16x8 al, s16x8 bh, f32x4 c){
    c = mfma16(ah, bh, c);
    c = mfma16(al, bh, c);
    return c;
}
__device__ __forceinline__ f32x4 z4(){ f32x4 v = {0.f,0.f,0.f,0.f}; return v; }

// XCD-aware swizzle (r10: FETCH 70->12 MB). All blocks on one XCD share bg
// in {2*xcd, 2*xcd+1}; per-XCD L2 holds 2 bgs' sweep operands.
__device__ __forceinline__ void xcd_map(int& bg, int& tile){
    int lb = blockIdx.y*32 + blockIdx.x;
    int xcd = lb & 7, t = lb >> 3;
    bg = 2*xcd + (t >> 5);
    tile = t & 31;
}

// ---------------- prep kernels ----------------

// hi+lo planes (mu only -- k_final phase B keeps fp32-emulated mu)
__global__ void k_convert(const float* __restrict__ src, u16* __restrict__ dh,
                          u16* __restrict__ dl, int n4)
{
    int idx = blockIdx.x*256 + threadIdx.x;
    if (idx >= n4) return;
    float4 v = ((const float4*)src)[idx];
    ushort4 h, l;
    split2(v.x, h.x, l.x); split2(v.y, h.y, l.y);
    split2(v.z, h.z, l.z); split2(v.w, h.w, l.w);
    ((ushort4*)dh)[idx] = h;
    ((ushort4*)dl)[idx] = l;
}

// hi-only convert (q natural layout -- lo plane is dead everywhere)
__global__ void k_convert1(const float* __restrict__ src, u16* __restrict__ dh, int n4)
{
    int idx = blockIdx.x*256 + threadIdx.x;
    if (idx >= n4) return;
    float4 v = ((const float4*)src)[idx];
    ushort4 h;
    h.x = f2bf(v.x); h.y = f2bf(v.y); h.z = f2bf(v.z); h.w = f2bf(v.w);
    ((ushort4*)dh)[idx] = h;
}

// hi-only transpose (q^T, z^T -- lo planes dead since r15)
__global__ void k_transpose1(const float* __restrict__ src, u16* __restrict__ dh)
{
    int bg = blockIdx.y, h0 = blockIdx.x*128, tid = threadIdx.x;
    __shared__ float ft[CD][132];
    #pragma unroll
    for (int k=0;k<8;k++){
        int flat = tid + 256*k;
        int c = flat >> 5, p = (flat & 31)*4;
        *(float4*)&ft[c][p] = *(const float4*)(src + ((size_t)bg*CD + c)*HD + h0 + p);
    }
    __syncthreads();
    int hl = tid >> 1, c0 = (tid & 1)*32;
    union { u16 u[32]; uint4 q[4]; } oh;
    #pragma unroll
    for (int m=0;m<32;m++)
        oh.u[m] = f2bf(ft[c0+m][hl]);
    size_t base = ((size_t)bg*HD + h0 + hl)*CD + c0;
    #pragma unroll
    for (int t=0;t<4;t++)
        *((uint4*)(dh + base) + t) = oh.q[t];
}

__global__ void k_bias(const float* __restrict__ mu, const float* __restrict__ beta,
                       float* __restrict__ bias)
{
    int bg = blockIdx.y;
    int j  = blockIdx.x*256 + threadIdx.x;
    const float* m = mu + (size_t)bg*CD*HD + j;
    float s = 0.f;
    #pragma unroll
    for (int c=0;c<CD;c++){ float v = m[(size_t)c*HD]; s = fmaf(v, v, s); }
    bias[(size_t)bg*HD + j] = 0.5f * beta[0] * s;
}

// ---------------- main MFMA kernels ----------------
// Precision scheme (r12-r16): all softmax logits hi-only bf16, each softmax exactly
// normalized against its own rounded weights (num/den share rounded values). zeta
// numerator uses hi-only q (zeta is stored bf16 anyway; q-rounding averages down by
// sqrt(Neff) under the softmax weights -- below zeta's own storage rounding). Only
// k_final's value matmul (e x mu) keeps hi/lo fp32 emulation (first-order on out).
// absmax pinned at 2^-11 through every step.
// r17 lesson: the allocator hard-caps (256,2) kernels at 128 arch VGPRs and SPILLS
// past it -- cross-step register pipelines are not expressible here. r16 is the
// measured optimum of this structure.

// r[i] = sum_j exp(a*S~+bias_j), S~ = hi-only bf16 S.
__global__ __launch_bounds__(256,2) void k_rowsum(
    const u16* __restrict__ qTh,
    const u16* __restrict__ zTh,
    const float* __restrict__ bias, const float* __restrict__ alpha,
    float* __restrict__ r)
{
    int bg, itile; xcd_map(bg, itile);
    const int i0 = itile*64;
    const int tid = threadIdx.x, wave = tid>>6, lane = tid&63, ln = lane&15, quad = lane>>4;
    const int jw = wave*32;
    const float a = alpha[0];
    __shared__ float rpart[4][64];

    s16x8 Ah[4][2];               // resident q^T frags (hi only): rows i0..i0+63
    #pragma unroll
    for (int mt=0;mt<4;mt++)
        #pragma unroll
        for (int ks=0;ks<2;ks++){
            size_t off = ((size_t)bg*HD + i0 + mt*16 + ln)*CD + ks*32 + quad*8;
            Ah[mt][ks] = ld8(qTh + off);
        }
    float racc[16];
    #pragma unroll
    for (int k=0;k<16;k++) racc[k] = 0.f;
    const float* bb = bias + (size_t)bg*HD;

    s16x8 B0h[2][2], B1h[2][2];
    float bj0[2], bj1[2];

    // prologue: tile 0
    #pragma unroll
    for (int nt=0;nt<2;nt++){
        #pragma unroll
        for (int ks=0;ks<2;ks++){
            size_t off = ((size_t)bg*HD + jw + nt*16 + ln)*CD + ks*32 + quad*8;
            B0h[nt][ks] = ld8(zTh + off);
        }
        bj0[nt] = bb[jw + nt*16 + ln];
    }

    for (int j0=0;j0<HD;j0+=256){
        // issue loads for tile j0+128 into B1, pinned above the B0 compute
        #pragma unroll
        for (int nt=0;nt<2;nt++){
            #pragma unroll
            for (int ks=0;ks<2;ks++){
                size_t off = ((size_t)bg*HD + j0+128 + jw + nt*16 + ln)*CD + ks*32 + quad*8;
                B1h[nt][ks] = ld8(zTh + off);
            }
            bj1[nt] = bb[j0+128 + jw + nt*16 + ln];
        }
        __builtin_amdgcn_sched_barrier(0);
        // compute tile j0 with B0
        {
            f32x4 acc[4][2];
            #pragma unroll
            for (int mt=0;mt<4;mt++){ acc[mt][0]=z4(); acc[mt][1]=z4(); }
            __builtin_amdgcn_s_setprio(1);
            #pragma unroll
            for (int ks=0;ks<2;ks++)
                #pragma unroll
                for (int mt=0;mt<4;mt++)
                    #pragma unroll
                    for (int nt=0;nt<2;nt++)
                        acc[mt][nt] = mfma16(Ah[mt][ks], B0h[nt][ks], acc[mt][nt]);
            __builtin_amdgcn_s_setprio(0);
            #pragma unroll
            for (int mt=0;mt<4;mt++)
                #pragma unroll
                for (int nt=0;nt<2;nt++)
                    #pragma unroll
                    for (int rx=0;rx<4;rx++)
                        racc[mt*4+rx] += __expf(fmaf(a, acc[mt][nt][rx], bj0[nt]));
        }
        // issue loads for tile (j0+256)&(HD-1) into B0, pinned above the B1 compute
        {
            int jn2 = (j0+256) & (HD-1);
            #pragma unroll
            for (int nt=0;nt<2;nt++){
                #pragma unroll
                for (int ks=0;ks<2;ks++){
                    size_t off = ((size_t)bg*HD + jn2 + jw + nt*16 + ln)*CD + ks*32 + quad*8;
                    B0h[nt][ks] = ld8(zTh + off);
                }
                bj0[nt] = bb[jn2 + jw + nt*16 + ln];
            }
        }
        __builtin_amdgcn_sched_barrier(0);
        // compute tile j0+128 with B1
        {
            f32x4 acc[4][2];
            #pragma unroll
            for (int mt=0;mt<4;mt++){ acc[mt][0]=z4(); acc[mt][1]=z4(); }
            __builtin_amdgcn_s_setprio(1);
            #pragma unroll
            for (int ks=0;ks<2;ks++)
                #pragma unroll
                for (int mt=0;mt<4;mt++)
                    #pragma unroll
                    for (int nt=0;nt<2;nt++)
                        acc[mt][nt] = mfma16(Ah[mt][ks], B1h[nt][ks], acc[mt][nt]);
            __builtin_amdgcn_s_setprio(0);
            #pragma unroll
            for (int mt=0;mt<4;mt++)
                #pragma unroll
                for (int nt=0;nt<2;nt++)
                    #pragma unroll
                    for (int rx=0;rx<4;rx++)
                        racc[mt*4+rx] += __expf(fmaf(a, acc[mt][nt][rx], bj1[nt]));
        }
    }
    #pragma unroll
    for (int k=0;k<16;k++){
        float v = racc[k];
        v += __shfl_xor(v,1); v += __shfl_xor(v,2);
        v += __shfl_xor(v,4); v += __shfl_xor(v,8);
        racc[k] = v;
    }
    if (ln == 0){
        #pragma unroll
        for (int mt=0;mt<4;mt++)
            #pragma unroll
            for (int rx=0;rx<4;rx++)
                rpart[wave][mt*16 + quad*4 + rx] = racc[mt*4+rx];
    }
    __syncthreads();
    if (tid < 64)
        r[(size_t)bg*HD + i0 + tid] = rpart[0][tid]+rpart[1][tid]+rpart[2][tid]+rpart[3][tid];
}

// zeta update. Phase A hi-only S~ (r14). Phase B hi-only qN (r16). w single-plane
// LDS, den from rounded w (r13). Epilogue writes zTh only.
__global__ __launch_bounds__(256,2) void k_update(
    const u16* __restrict__ qTh,
    u16* zTh,                                          // read then overwritten (own rows only)
    const u16* __restrict__ qNh,
    const float* __restrict__ bias, const float* __restrict__ alpha,
    const float* __restrict__ r)
{
    int bg, jtile; xcd_map(bg, jtile);
    const int j0 = jtile*64;
    const int tid = threadIdx.x, wave = tid>>6, lane = tid&63, ln = lane&15, quad = lane>>4;
    const int cm = (wave&1)*32, jn = (wave>>1)*32;
    const float a = alpha[0];
    __shared__ u16 wl[2][64*128];                     // double-buffered w^T [j][i], swizzled, 1 plane
    __shared__ float denl[4][64];

    s16x8 Bh[4][2];               // resident z^T frags (hi only): rows j0..j0+63
    #pragma unroll
    for (int nt=0;nt<4;nt++)
        #pragma unroll
        for (int ks=0;ks<2;ks++){
            size_t off = ((size_t)bg*HD + j0 + nt*16 + ln)*CD + ks*32 + quad*8;
            Bh[nt][ks] = ld8(zTh + off);
        }
    float bj[4];
    #pragma unroll
    for (int nt=0;nt<4;nt++) bj[nt] = bias[(size_t)bg*HD + j0 + nt*16 + ln];

    f32x4 acc2[2][2] = {{z4(),z4()},{z4(),z4()}};
    float den[4] = {0.f,0.f,0.f,0.f};
    int buf = 0;

    for (int is=0; is<HD; is+=128, buf^=1){
        // ---- issue phase-A operand loads (q^T hi only) ----
        s16x8 Ah[2][2];
        #pragma unroll
        for (int ks=0;ks<2;ks++)
            #pragma unroll
            for (int mt=0;mt<2;mt++){
                size_t off = ((size_t)bg*HD + is + wave*32 + mt*16 + ln)*CD + ks*32 + quad*8;
                Ah[mt][ks] = ld8(qTh + off);
            }
        // ---- issue ALL phase-B operand loads (qN hi only) ----
        s16x8 A2h[4][2];
        #pragma unroll
        for (int ks2=0;ks2<4;ks2++)
            #pragma unroll
            for (int mtN=0;mtN<2;mtN++){
                size_t off = ((size_t)bg*CD + cm + mtN*16 + ln)*HD + is + ks2*32 + quad*8;
                A2h[ks2][mtN] = ld8(qNh + off);
            }
        // ---- r loads (vectorized) ----
        float ri[8];
        #pragma unroll
        for (int mt=0;mt<2;mt++){
            float4 rv = *(const float4*)&r[(size_t)bg*HD + is + wave*32 + mt*16 + quad*4];
            ri[mt*4+0] = __builtin_amdgcn_rcpf(rv.x);
            ri[mt*4+1] = __builtin_amdgcn_rcpf(rv.y);
            ri[mt*4+2] = __builtin_amdgcn_rcpf(rv.z);
            ri[mt*4+3] = __builtin_amdgcn_rcpf(rv.w);
        }
        // PIN: no load above may sink below this point.
        __builtin_amdgcn_sched_barrier(0);
        // ---- phase A MFMA (hi-only) ----
        f32x4 acc1[2][4];
        #pragma unroll
        for (int mt=0;mt<2;mt++)
            #pragma unroll
            for (int nt=0;nt<4;nt++) acc1[mt][nt] = z4();
        __builtin_amdgcn_s_setprio(1);
        #pragma unroll
        for (int ks=0;ks<2;ks++)
            #pragma unroll
            for (int mt=0;mt<2;mt++)
                #pragma unroll
                for (int nt=0;nt<4;nt++)
                    acc1[mt][nt] = mfma16(Ah[mt][ks], Bh[nt][ks], acc1[mt][nt]);
        __builtin_amdgcn_s_setprio(0);
        // ---- w compute + LDS write (buffer `buf`); den uses the ROUNDED w ----
        #pragma unroll
        for (int mt=0;mt<2;mt++)
            #pragma unroll
            for (int nt=0;nt<4;nt++){
                u16 hh[4];
                #pragma unroll
                for (int rx=0;rx<4;rx++){
                    float w = __expf(fmaf(a, acc1[mt][nt][rx], bj[nt])) * ri[mt*4+rx];
                    hh[rx] = f2bf(w);
                    den[nt] += bf2f(hh[rx]);
                }
                int row = nt*16 + ln;                        // j-local
                int c4  = wave*32 + mt*16 + quad*4;          // i-local
                int off = (row<<7) + ((((c4>>3) ^ (row&15))<<3) | (c4&7));
                *(ushort4*)&wl[buf][off] = make_ushort4(hh[0],hh[1],hh[2],hh[3]);
            }
        __syncthreads();
        // ---- phase B: LDS reads + MFMA (hi-only both operands) ----
        __builtin_amdgcn_s_setprio(1);
        #pragma unroll
        for (int ks2=0;ks2<4;ks2++){
            s16x8 B2h[2];
            #pragma unroll
            for (int nt2=0;nt2<2;nt2++){
                int jl = jn + nt2*16 + ln;
                int ob = (jl<<7) + (((ks2*4+quad) ^ (jl&15))<<3);
                B2h[nt2] = ld8(&wl[buf][ob]);
            }
            #pragma unroll
            for (int mtN=0;mtN<2;mtN++)
                #pragma unroll
                for (int nt2=0;nt2<2;nt2++)
                    acc2[mtN][nt2] = mfma16(A2h[ks2][mtN], B2h[nt2], acc2[mtN][nt2]);
        }
        __builtin_amdgcn_s_setprio(0);
    }
    // denominator reduce: quads via shfl, waves via LDS
    #pragma unroll
    for (int nt=0;nt<4;nt++){
        float v = den[nt];
        v += __shfl_xor(v,16); v += __shfl_xor(v,32);
        if (quad == 0) denl[wave][nt*16 + ln] = v;
    }
    __syncthreads();
    #pragma unroll
    for (int nt2=0;nt2<2;nt2++){
        int jl = jn + nt2*16 + ln;
        float dinv = __builtin_amdgcn_rcpf(denl[0][jl]+denl[1][jl]+denl[2][jl]+denl[3][jl]);
        #pragma unroll
        for (int mtN=0;mtN<2;mtN++){
            u16 hh[4];
            #pragma unroll
            for (int rx=0;rx<4;rx++)
                hh[rx] = f2bf(acc2[mtN][nt2][rx] * dinv);
            size_t off = ((size_t)bg*HD + j0 + jl)*CD + cm + mtN*16 + quad*4;
            *(ushort4*)(zTh + off) = make_ushort4(hh[0],hh[1],hh[2],hh[3]);
        }
    }
}

// final: out[c][i] = (sum_j e~_ij mu_cj) / (sum_j e~_ij). Phase A hi-only (r15);
// phase B KEEPS hi/lo mu (mm2) -- mu rounding is first-order on the fp32 output.
__global__ __launch_bounds__(256,2) void k_final(
    const u16* __restrict__ qTh,
    const u16* __restrict__ zTh,
    const u16* __restrict__ muh, const u16* __restrict__ mul_,
    const float* __restrict__ bias, const float* __restrict__ alpha,
    float* __restrict__ out)
{
    int bg, itile; xcd_map(bg, itile);
    const int i0 = itile*64;
    const int tid = threadIdx.x, wave = tid>>6, lane = tid&63, ln = lane&15, quad = lane>>4;
    const int cm = (wave&1)*32, in_ = (wave>>1)*32;
    const float a = alpha[0];
    __shared__ u16 el[2][64*128];                     // double-buffered e^T [i][j], swizzled, 1 plane
    __shared__ float rl2[4][64];

    s16x8 Bh[4][2];               // resident q^T frags (hi only): rows i0..i0+63 (n operand)
    #pragma unroll
    for (int nt=0;nt<4;nt++)
        #pragma unroll
        for (int ks=0;ks<2;ks++){
            size_t off = ((size_t)bg*HD + i0 + nt*16 + ln)*CD + ks*32 + quad*8;
            Bh[nt][ks] = ld8(qTh + off);
        }
    f32x4 acc2[2][2] = {{z4(),z4()},{z4(),z4()}};
    float racc[4] = {0.f,0.f,0.f,0.f};
    int buf = 0;

    for (int js=0; js<HD; js+=128, buf^=1){
        // ---- issue phase-A operand loads (z^T hi only) ----
        s16x8 Ah[2][2];
        #pragma unroll
        for (int ks=0;ks<2;ks++)
            #pragma unroll
            for (int mt=0;mt<2;mt++){
                size_t off = ((size_t)bg*HD + js + wave*32 + mt*16 + ln)*CD + ks*32 + quad*8;
                Ah[mt][ks] = ld8(zTh + off);
            }
        // ---- issue ALL phase-B operand loads (mu hi/lo) ----
        s16x8 A2h[4][2], A2l[4][2];
        #pragma unroll
        for (int ks2=0;ks2<4;ks2++)
            #pragma unroll
            for (int mtN=0;mtN<2;mtN++){
                size_t off = ((size_t)bg*CD + cm + mtN*16 + ln)*HD + js + ks2*32 + quad*8;
                A2h[ks2][mtN] = ld8(muh + off);
                A2l[ks2][mtN] = ld8(mul_ + off);
            }
        // ---- bias loads (vectorized) ----
        float bj8[8];
        #pragma unroll
        for (int mt=0;mt<2;mt++){
            float4 bv = *(const float4*)&bias[(size_t)bg*HD + js + wave*32 + mt*16 + quad*4];
            bj8[mt*4+0]=bv.x; bj8[mt*4+1]=bv.y; bj8[mt*4+2]=bv.z; bj8[mt*4+3]=bv.w;
        }
        // PIN: loads may not sink below.
        __builtin_amdgcn_sched_barrier(0);
        // ---- phase A MFMA (hi-only): S'[j][i] (m = j, n = i) ----
        f32x4 acc1[2][4];
        #pragma unroll
        for (int mt=0;mt<2;mt++)
            #pragma unroll
            for (int nt=0;nt<4;nt++) acc1[mt][nt] = z4();
        __builtin_amdgcn_s_setprio(1);
        #pragma unroll
        for (int ks=0;ks<2;ks++)
            #pragma unroll
            for (int mt=0;mt<2;mt++)
                #pragma unroll
                for (int nt=0;nt<4;nt++)
                    acc1[mt][nt] = mfma16(Ah[mt][ks], Bh[nt][ks], acc1[mt][nt]);
        __builtin_amdgcn_s_setprio(0);
        // ---- e compute + LDS write (buffer `buf`); racc uses the ROUNDED e ----
        #pragma unroll
        for (int mt=0;mt<2;mt++)
            #pragma unroll
            for (int nt=0;nt<4;nt++){
                u16 hh[4];
                #pragma unroll
                for (int rx=0;rx<4;rx++){
                    float e = __expf(fmaf(a, acc1[mt][nt][rx], bj8[mt*4+rx]));
                    hh[rx] = f2bf(e);
                    racc[nt] += bf2f(hh[rx]);
                }
                int row = nt*16 + ln;                        // i-local
                int c4  = wave*32 + mt*16 + quad*4;          // j-local
                int off = (row<<7) + ((((c4>>3) ^ (row&15))<<3) | (c4&7));
                *(ushort4*)&el[buf][off] = make_ushort4(hh[0],hh[1],hh[2],hh[3]);
            }
        __syncthreads();
        // ---- phase B: acc2[c][i] += mu * e^T ----
        __builtin_amdgcn_s_setprio(1);
        #pragma unroll
        for (int ks2=0;ks2<4;ks2++){
            s16x8 B2h[2];
            #pragma unroll
            for (int nt2=0;nt2<2;nt2++){
                int il = in_ + nt2*16 + ln;
                int ob = (il<<7) + (((ks2*4+quad) ^ (il&15))<<3);
                B2h[nt2] = ld8(&el[buf][ob]);
            }
            #pragma unroll
            for (int mtN=0;mtN<2;mtN++)
                #pragma unroll
                for (int nt2=0;nt2<2;nt2++)
                    acc2[mtN][nt2] = mm2(A2h[ks2][mtN], A2l[ks2][mtN], B2h[nt2], acc2[mtN][nt2]);
        }
        __builtin_amdgcn_s_setprio(0);
    }
    #pragma unroll
    for (int nt=0;nt<4;nt++){
        float v = racc[nt];
        v += __shfl_xor(v,16); v += __shfl_xor(v,32);
        if (quad == 0) rl2[wave][nt*16 + ln] = v;
    }
    __syncthreads();
    #pragma unroll
    for (int nt2=0;nt2<2;nt2++){
        int il = in_ + nt2*16 + ln;
        float rinv = __builtin_amdgcn_rcpf(rl2[0][il]+rl2[1][il]+rl2[2][il]+rl2[3][il]);
        #pragma unroll
        for (int mtN=0;mtN<2;mtN++)
            #pragma unroll
            for (int rx=0;rx<4;rx++)
                out[((size_t)bg*CD + cm + mtN*16 + quad*4 + rx)*HD + i0 + il]
                    = acc2[mtN][nt2][rx] * rinv;
    }
}

extern "C" void kernel_launch(void* const* d_in, const int* in_sizes, int n_in,
                              void* d_out, int out_size, void* d_ws, size_t ws_size,
                              hipStream_t stream)
{
    (void)in_sizes; (void)n_in; (void)out_size; (void)ws_size;
    const float* q     = (const float*)d_in[0];
    const float* zeta  = (const float*)d_in[1];
    const float* alpha = (const float*)d_in[2];
    const float* mu    = (const float*)d_in[3];
    const float* beta  = (const float*)d_in[4];
    float* out = (float*)d_out;

    const size_t SZ = (size_t)NB*HD*CD;   // elements per tensor
    u16* qTh = (u16*)d_ws;
    u16* zTh = qTh + 1*SZ;
    u16* qNh = qTh + 2*SZ;
    u16* muh = qTh + 3*SZ;
    u16* mul_= qTh + 4*SZ;
    float* bias = (float*)(qTh + 5*SZ);
    float* r    = bias + (size_t)NB*HD;

    dim3 blk(256,1,1);
    int n4 = (int)(SZ/4);
    k_convert1 <<<dim3(n4/256), blk, 0, stream>>>(q,  qNh, n4);
    k_convert  <<<dim3(n4/256), blk, 0, stream>>>(mu, muh, mul_, n4);
    k_transpose1<<<dim3(HD/128, NB), blk, 0, stream>>>(q,    qTh);
    k_transpose1<<<dim3(HD/128, NB), blk, 0, stream>>>(zeta, zTh);
    k_bias     <<<dim3(HD/256, NB), blk, 0, stream>>>(mu, beta, bias);

    k_rowsum<<<dim3(HD/64, NB), blk, 0, stream>>>(qTh,zTh,bias,alpha,r);
    k_update<<<dim3(HD/64, NB), blk, 0, stream>>>(qTh,zTh,qNh,bias,alpha,r);
    k_rowsum<<<dim3(HD/64, NB), blk, 0, stream>>>(qTh,zTh,bias,alpha,r);
    k_update<<<dim3(HD/64, NB), blk, 0, stream>>>(qTh,zTh,qNh,bias,alpha,r);
    k_final <<<dim3(HD/64, NB), blk, 0, stream>>>(qTh,zTh,muh,mul_,bias,alpha,out);
}

// Round 20
// 303.500 us; speedup vs baseline: 1.1435x; 1.0966x over previous
//
#include <hip/hip_runtime.h>

#define NB 16    // N*G
#define CD 64    // C == Cv
#define HD 2048  // H

typedef unsigned short u16;
typedef __attribute__((ext_vector_type(8))) short s16x8;  // 8 bf16 (4 VGPRs)
typedef __attribute__((ext_vector_type(4))) float f32x4;  // MFMA C/D

__device__ __forceinline__ u16 f2bf(float x){
    unsigned u = __float_as_uint(x);
    u += 0x7FFFu + ((u >> 16) & 1u);   // RNE
    return (u16)(u >> 16);
}
__device__ __forceinline__ float bf2f(u16 h){ return __uint_as_float(((unsigned)h) << 16); }
__device__ __forceinline__ void split2(float x, u16& h, u16& l){
    h = f2bf(x); l = f2bf(x - bf2f(h));   // x - hi is exact in fp32
}
union Frag { uint4 q; s16x8 s; };
__device__ __forceinline__ s16x8 ld8(const u16* p){ Frag f; f.q = *(const uint4*)p; return f.s; }
__device__ __forceinline__ f32x4 mfma16(s16x8 a, s16x8 b, f32x4 c){
    return __builtin_amdgcn_mfma_f32_16x16x32_bf16(a, b, c, 0, 0, 0);
}
// hi/lo A against single-plane B (B pre-rounded to bf16 consistently with its sum)
__device__ __forceinline__ f32x4 mm2(s16x8 ah, s16x8 al, s16x8 bh, f32x4 c){
    c = mfma16(ah, bh, c);
    c = mfma16(al, bh, c);
    return c;
}
__device__ __forceinline__ f32x4 z4(){ f32x4 v = {0.f,0.f,0.f,0.f}; return v; }

// XCD-aware swizzle (r10: FETCH 70->12 MB). All blocks on one XCD share bg
// in {2*xcd, 2*xcd+1}; per-XCD L2 holds 2 bgs' sweep operands.
__device__ __forceinline__ void xcd_map(int& bg, int& tile){
    int lb = blockIdx.y*32 + blockIdx.x;
    int xcd = lb & 7, t = lb >> 3;
    bg = 2*xcd + (t >> 5);
    tile = t & 31;
}

// LDS staging swizzle: tile byte F (row = F>>7, 128B rows) -> XOR byte-bits 4..6
// with row&7. Read of a 16B slot at (row, o): ad = row*128 + (o ^ ((row&7)<<4)).
// Spreads the 16 ln-lanes of a fragment read across 8 bank-groups (2-way = free).
__device__ __forceinline__ int stg_swz(int F){
    return (F & ~127) | ((F & 127) ^ (((F >> 7) & 7) << 4));
}

// ---------------- prep kernels ----------------

// hi+lo planes (mu only -- k_final phase B keeps fp32-emulated mu)
__global__ void k_convert(const float* __restrict__ src, u16* __restrict__ dh,
                          u16* __restrict__ dl, int n4)
{
    int idx = blockIdx.x*256 + threadIdx.x;
    if (idx >= n4) return;
    float4 v = ((const float4*)src)[idx];
    ushort4 h, l;
    split2(v.x, h.x, l.x); split2(v.y, h.y, l.y);
    split2(v.z, h.z, l.z); split2(v.w, h.w, l.w);
    ((ushort4*)dh)[idx] = h;
    ((ushort4*)dl)[idx] = l;
}

// hi-only convert (q natural layout -- lo plane is dead everywhere)
__global__ void k_convert1(const float* __restrict__ src, u16* __restrict__ dh, int n4)
{
    int idx = blockIdx.x*256 + threadIdx.x;
    if (idx >= n4) return;
    float4 v = ((const float4*)src)[idx];
    ushort4 h;
    h.x = f2bf(v.x); h.y = f2bf(v.y); h.z = f2bf(v.z); h.w = f2bf(v.w);
    ((ushort4*)dh)[idx] = h;
}

// hi-only transpose (q^T, z^T)
__global__ void k_transpose1(const float* __restrict__ src, u16* __restrict__ dh)
{
    int bg = blockIdx.y, h0 = blockIdx.x*128, tid = threadIdx.x;
    __shared__ float ft[CD][132];
    #pragma unroll
    for (int k=0;k<8;k++){
        int flat = tid + 256*k;
        int c = flat >> 5, p = (flat & 31)*4;
        *(float4*)&ft[c][p] = *(const float4*)(src + ((size_t)bg*CD + c)*HD + h0 + p);
    }
    __syncthreads();
    int hl = tid >> 1, c0 = (tid & 1)*32;
    union { u16 u[32]; uint4 q[4]; } oh;
    #pragma unroll
    for (int m=0;m<32;m++)
        oh.u[m] = f2bf(ft[c0+m][hl]);
    size_t base = ((size_t)bg*HD + h0 + hl)*CD + c0;
    #pragma unroll
    for (int t=0;t<4;t++)
        *((uint4*)(dh + base) + t) = oh.q[t];
}

__global__ void k_bias(const float* __restrict__ mu, const float* __restrict__ beta,
                       float* __restrict__ bias)
{
    int bg = blockIdx.y;
    int j  = blockIdx.x*256 + threadIdx.x;
    const float* m = mu + (size_t)bg*CD*HD + j;
    float s = 0.f;
    #pragma unroll
    for (int c=0;c<CD;c++){ float v = m[(size_t)c*HD]; s = fmaf(v, v, s); }
    bias[(size_t)bg*HD + j] = 0.5f * beta[0] * s;
}

// ---------------- main MFMA kernels ----------------
// Precision scheme (r12-r16, absmax pinned 2^-11): all softmax logits hi-only bf16,
// each softmax exactly normalized against its own rounded weights; zeta numerator
// hi-only q; only k_final's e x mu keeps hi/lo fp32 emulation.
// r19: phase-A operands (qT / zT) double-buffered in LDS -- prefetch parks in LDS,
// bypassing the 128-VGPR allocator cap that killed register pipelines (r17).
// Self-staged per wave: wave w stages/reads ONLY its own 32 rows (4KB slice), so
// ordering is same-wave lgkmcnt only; no cross-wave races (buffers alternate and
// reads of buf vs writes of buf^1 are disjoint).

// r[i] = sum_j exp(a*S~+bias_j), S~ = hi-only bf16 S. (unchanged r16)
__global__ __launch_bounds__(256,2) void k_rowsum(
    const u16* __restrict__ qTh,
    const u16* __restrict__ zTh,
    const float* __restrict__ bias, const float* __restrict__ alpha,
    float* __restrict__ r)
{
    int bg, itile; xcd_map(bg, itile);
    const int i0 = itile*64;
    const int tid = threadIdx.x, wave = tid>>6, lane = tid&63, ln = lane&15, quad = lane>>4;
    const int jw = wave*32;
    const float a = alpha[0];
    __shared__ float rpart[4][64];

    s16x8 Ah[4][2];               // resident q^T frags (hi only): rows i0..i0+63
    #pragma unroll
    for (int mt=0;mt<4;mt++)
        #pragma unroll
        for (int ks=0;ks<2;ks++){
            size_t off = ((size_t)bg*HD + i0 + mt*16 + ln)*CD + ks*32 + quad*8;
            Ah[mt][ks] = ld8(qTh + off);
        }
    float racc[16];
    #pragma unroll
    for (int k=0;k<16;k++) racc[k] = 0.f;
    const float* bb = bias + (size_t)bg*HD;

    s16x8 B0h[2][2], B1h[2][2];
    float bj0[2], bj1[2];

    #pragma unroll
    for (int nt=0;nt<2;nt++){
        #pragma unroll
        for (int ks=0;ks<2;ks++){
            size_t off = ((size_t)bg*HD + jw + nt*16 + ln)*CD + ks*32 + quad*8;
            B0h[nt][ks] = ld8(zTh + off);
        }
        bj0[nt] = bb[jw + nt*16 + ln];
    }

    for (int j0=0;j0<HD;j0+=256){
        #pragma unroll
        for (int nt=0;nt<2;nt++){
            #pragma unroll
            for (int ks=0;ks<2;ks++){
                size_t off = ((size_t)bg*HD + j0+128 + jw + nt*16 + ln)*CD + ks*32 + quad*8;
                B1h[nt][ks] = ld8(zTh + off);
            }
            bj1[nt] = bb[j0+128 + jw + nt*16 + ln];
        }
        __builtin_amdgcn_sched_barrier(0);
        {
            f32x4 acc[4][2];
            #pragma unroll
            for (int mt=0;mt<4;mt++){ acc[mt][0]=z4(); acc[mt][1]=z4(); }
            __builtin_amdgcn_s_setprio(1);
            #pragma unroll
            for (int ks=0;ks<2;ks++)
                #pragma unroll
                for (int mt=0;mt<4;mt++)
                    #pragma unroll
                    for (int nt=0;nt<2;nt++)
                        acc[mt][nt] = mfma16(Ah[mt][ks], B0h[nt][ks], acc[mt][nt]);
            __builtin_amdgcn_s_setprio(0);
            #pragma unroll
            for (int mt=0;mt<4;mt++)
                #pragma unroll
                for (int nt=0;nt<2;nt++)
                    #pragma unroll
                    for (int rx=0;rx<4;rx++)
                        racc[mt*4+rx] += __expf(fmaf(a, acc[mt][nt][rx], bj0[nt]));
        }
        {
            int jn2 = (j0+256) & (HD-1);
            #pragma unroll
            for (int nt=0;nt<2;nt++){
                #pragma unroll
                for (int ks=0;ks<2;ks++){
                    size_t off = ((size_t)bg*HD + jn2 + jw + nt*16 + ln)*CD + ks*32 + quad*8;
                    B0h[nt][ks] = ld8(zTh + off);
                }
                bj0[nt] = bb[jn2 + jw + nt*16 + ln];
            }
        }
        __builtin_amdgcn_sched_barrier(0);
        {
            f32x4 acc[4][2];
            #pragma unroll
            for (int mt=0;mt<4;mt++){ acc[mt][0]=z4(); acc[mt][1]=z4(); }
            __builtin_amdgcn_s_setprio(1);
            #pragma unroll
            for (int ks=0;ks<2;ks++)
                #pragma unroll
                for (int mt=0;mt<4;mt++)
                    #pragma unroll
                    for (int nt=0;nt<2;nt++)
                        acc[mt][nt] = mfma16(Ah[mt][ks], B1h[nt][ks], acc[mt][nt]);
            __builtin_amdgcn_s_setprio(0);
            #pragma unroll
            for (int mt=0;mt<4;mt++)
                #pragma unroll
                for (int nt=0;nt<2;nt++)
                    #pragma unroll
                    for (int rx=0;rx<4;rx++)
                        racc[mt*4+rx] += __expf(fmaf(a, acc[mt][nt][rx], bj1[nt]));
        }
    }
    #pragma unroll
    for (int k=0;k<16;k++){
        float v = racc[k];
        v += __shfl_xor(v,1); v += __shfl_xor(v,2);
        v += __shfl_xor(v,4); v += __shfl_xor(v,8);
        racc[k] = v;
    }
    if (ln == 0){
        #pragma unroll
        for (int mt=0;mt<4;mt++)
            #pragma unroll
            for (int rx=0;rx<4;rx++)
                rpart[wave][mt*16 + quad*4 + rx] = racc[mt*4+rx];
    }
    __syncthreads();
    if (tid < 64)
        r[(size_t)bg*HD + i0 + tid] = rpart[0][tid]+rpart[1][tid]+rpart[2][tid]+rpart[3][tid];
}

// zeta update. Phase A reads qT from LDS staging (qs, swizzled, double-buffered);
// next tile staged per wave under the w-block + barrier + phase B.
__global__ __launch_bounds__(256,2) void k_update(
    const u16* __restrict__ qTh,
    u16* zTh,                                          // read then overwritten (own rows only)
    const u16* __restrict__ qNh,
    const float* __restrict__ bias, const float* __restrict__ alpha,
    const float* __restrict__ r)
{
    int bg, jtile; xcd_map(bg, jtile);
    const int j0 = jtile*64;
    const int tid = threadIdx.x, wave = tid>>6, lane = tid&63, ln = lane&15, quad = lane>>4;
    const int cm = (wave&1)*32, jn = (wave>>1)*32;
    const float a = alpha[0];
    __shared__ u16 wl[2][64*128];                     // w^T [j][i], swizzled, 1 plane
    __shared__ u16 qs[2][128*64];                     // staged qT tile [i-local][c], stg_swz
    __shared__ float denl[4][64];

    s16x8 Bh[4][2];               // resident z^T frags (hi only): rows j0..j0+63
    #pragma unroll
    for (int nt=0;nt<4;nt++)
        #pragma unroll
        for (int ks=0;ks<2;ks++){
            size_t off = ((size_t)bg*HD + j0 + nt*16 + ln)*CD + ks*32 + quad*8;
            Bh[nt][ks] = ld8(zTh + off);
        }
    float bj[4];
    #pragma unroll
    for (int nt=0;nt<4;nt++) bj[nt] = bias[(size_t)bg*HD + j0 + nt*16 + ln];

    // prologue: stage tile 0 (this wave's 32 rows, 4KB)
    {
        const u16* srcb = qTh + (size_t)bg*HD*CD;     // tile base @ is=0
        #pragma unroll
        for (int b=0;b<4;b++){
            int F = wave*4096 + lane*16 + b*1024;
            uint4 g = *(const uint4*)((const char*)srcb + F);
            *(uint4*)&qs[0][stg_swz(F)>>1] = g;
        }
    }

    f32x4 acc2[2][2] = {{z4(),z4()},{z4(),z4()}};
    float den[4] = {0.f,0.f,0.f,0.f};
    int buf = 0;

    for (int is=0; is<HD; is+=128, buf^=1){
        // ---- issue phase-B operand loads (qN hi only) ----
        s16x8 A2h[4][2];
        #pragma unroll
        for (int ks2=0;ks2<4;ks2++)
            #pragma unroll
            for (int mtN=0;mtN<2;mtN++){
                size_t off = ((size_t)bg*CD + cm + mtN*16 + ln)*HD + is + ks2*32 + quad*8;
                A2h[ks2][mtN] = ld8(qNh + off);
            }
        // ---- r loads (vectorized) ----
        float ri[8];
        #pragma unroll
        for (int mt=0;mt<2;mt++){
            float4 rv = *(const float4*)&r[(size_t)bg*HD + is + wave*32 + mt*16 + quad*4];
            ri[mt*4+0] = __builtin_amdgcn_rcpf(rv.x);
            ri[mt*4+1] = __builtin_amdgcn_rcpf(rv.y);
            ri[mt*4+2] = __builtin_amdgcn_rcpf(rv.z);
            ri[mt*4+3] = __builtin_amdgcn_rcpf(rv.w);
        }
        __builtin_amdgcn_sched_barrier(0);
        // ---- phase A: ds_read staged qT + MFMA (hi-only) ----
        f32x4 acc1[2][4];
        #pragma unroll
        for (int mt=0;mt<2;mt++)
            #pragma unroll
            for (int nt=0;nt<4;nt++) acc1[mt][nt] = z4();
        {
            s16x8 Ah[2][2];
            #pragma unroll
            for (int ks=0;ks<2;ks++)
                #pragma unroll
                for (int mt=0;mt<2;mt++){
                    int row = wave*32 + mt*16 + ln;
                    int o   = ks*64 + quad*16;
                    int ad  = row*128 + (o ^ ((row&7)<<4));
                    Ah[mt][ks] = ld8(&qs[buf][ad>>1]);
                }
            __builtin_amdgcn_s_setprio(1);
            #pragma unroll
            for (int ks=0;ks<2;ks++)
                #pragma unroll
                for (int mt=0;mt<2;mt++)
                    #pragma unroll
                    for (int nt=0;nt<4;nt++)
                        acc1[mt][nt] = mfma16(Ah[mt][ks], Bh[nt][ks], acc1[mt][nt]);
            __builtin_amdgcn_s_setprio(0);
        }
        // ---- issue staging loads for next tile (cover: w-block + barrier) ----
        const bool st = (is + 128 < HD);
        uint4 g0, g1, g2, g3;
        if (st){
            const char* srcb = (const char*)(qTh + ((size_t)bg*HD + is + 128)*CD);
            int F = wave*4096 + lane*16;
            g0 = *(const uint4*)(srcb + F);
            g1 = *(const uint4*)(srcb + F + 1024);
            g2 = *(const uint4*)(srcb + F + 2048);
            g3 = *(const uint4*)(srcb + F + 3072);
        }
        __builtin_amdgcn_sched_barrier(0);
        // ---- w compute + LDS write (buffer `buf`); den uses the ROUNDED w ----
        #pragma unroll
        for (int mt=0;mt<2;mt++)
            #pragma unroll
            for (int nt=0;nt<4;nt++){
                u16 hh[4];
                #pragma unroll
                for (int rx=0;rx<4;rx++){
                    float w = __expf(fmaf(a, acc1[mt][nt][rx], bj[nt])) * ri[mt*4+rx];
                    hh[rx] = f2bf(w);
                    den[nt] += bf2f(hh[rx]);
                }
                int row = nt*16 + ln;                        // j-local
                int c4  = wave*32 + mt*16 + quad*4;          // i-local
                int off = (row<<7) + ((((c4>>3) ^ (row&15))<<3) | (c4&7));
                *(ushort4*)&wl[buf][off] = make_ushort4(hh[0],hh[1],hh[2],hh[3]);
            }
        __syncthreads();
        // ---- staging writes (own-wave data only; ordered vs next phase A by lgkmcnt) ----
        if (st){
            int F = wave*4096 + lane*16;
            *(uint4*)&qs[buf^1][stg_swz(F       )>>1] = g0;
            *(uint4*)&qs[buf^1][stg_swz(F + 1024)>>1] = g1;
            *(uint4*)&qs[buf^1][stg_swz(F + 2048)>>1] = g2;
            *(uint4*)&qs[buf^1][stg_swz(F + 3072)>>1] = g3;
        }
        // ---- phase B: LDS reads + MFMA (hi-only both operands) ----
        __builtin_amdgcn_s_setprio(1);
        #pragma unroll
        for (int ks2=0;ks2<4;ks2++){
            s16x8 B2h[2];
            #pragma unroll
            for (int nt2=0;nt2<2;nt2++){
                int jl = jn + nt2*16 + ln;
                int ob = (jl<<7) + (((ks2*4+quad) ^ (jl&15))<<3);
                B2h[nt2] = ld8(&wl[buf][ob]);
            }
            #pragma unroll
            for (int mtN=0;mtN<2;mtN++)
                #pragma unroll
                for (int nt2=0;nt2<2;nt2++)
                    acc2[mtN][nt2] = mfma16(A2h[ks2][mtN], B2h[nt2], acc2[mtN][nt2]);
        }
        __builtin_amdgcn_s_setprio(0);
    }
    // denominator reduce
    #pragma unroll
    for (int nt=0;nt<4;nt++){
        float v = den[nt];
        v += __shfl_xor(v,16); v += __shfl_xor(v,32);
        if (quad == 0) denl[wave][nt*16 + ln] = v;
    }
    __syncthreads();
    #pragma unroll
    for (int nt2=0;nt2<2;nt2++){
        int jl = jn + nt2*16 + ln;
        float dinv = __builtin_amdgcn_rcpf(denl[0][jl]+denl[1][jl]+denl[2][jl]+denl[3][jl]);
        #pragma unroll
        for (int mtN=0;mtN<2;mtN++){
            u16 hh[4];
            #pragma unroll
            for (int rx=0;rx<4;rx++)
                hh[rx] = f2bf(acc2[mtN][nt2][rx] * dinv);
            size_t off = ((size_t)bg*HD + j0 + jl)*CD + cm + mtN*16 + quad*4;
            *(ushort4*)(zTh + off) = make_ushort4(hh[0],hh[1],hh[2],hh[3]);
        }
    }
}

// final: phase A reads zT from LDS staging (zs). Phase B keeps hi/lo mu (mm2).
__global__ __launch_bounds__(256,2) void k_final(
    const u16* __restrict__ qTh,
    const u16* __restrict__ zTh,
    const u16* __restrict__ muh, const u16* __restrict__ mul_,
    const float* __restrict__ bias, const float* __restrict__ alpha,
    float* __restrict__ out)
{
    int bg, itile; xcd_map(bg, itile);
    const int i0 = itile*64;
    const int tid = threadIdx.x, wave = tid>>6, lane = tid&63, ln = lane&15, quad = lane>>4;
    const int cm = (wave&1)*32, in_ = (wave>>1)*32;
    const float a = alpha[0];
    __shared__ u16 el[2][64*128];                     // e^T [i][j], swizzled, 1 plane
    __shared__ u16 zs[2][128*64];                     // staged zT tile, stg_swz
    __shared__ float rl2[4][64];

    s16x8 Bh[4][2];               // resident q^T frags (hi only): rows i0..i0+63 (n operand)
    #pragma unroll
    for (int nt=0;nt<4;nt++)
        #pragma unroll
        for (int ks=0;ks<2;ks++){
            size_t off = ((size_t)bg*HD + i0 + nt*16 + ln)*CD + ks*32 + quad*8;
            Bh[nt][ks] = ld8(qTh + off);
        }
    // prologue: stage tile 0
    {
        const u16* srcb = zTh + (size_t)bg*HD*CD;
        #pragma unroll
        for (int b=0;b<4;b++){
            int F = wave*4096 + lane*16 + b*1024;
            uint4 g = *(const uint4*)((const char*)srcb + F);
            *(uint4*)&zs[0][stg_swz(F)>>1] = g;
        }
    }
    f32x4 acc2[2][2] = {{z4(),z4()},{z4(),z4()}};
    float racc[4] = {0.f,0.f,0.f,0.f};
    int buf = 0;

    for (int js=0; js<HD; js+=128, buf^=1){
        // ---- issue phase-B operand loads (mu hi/lo) ----
        s16x8 A2h[4][2], A2l[4][2];
        #pragma unroll
        for (int ks2=0;ks2<4;ks2++)
            #pragma unroll
            for (int mtN=0;mtN<2;mtN++){
                size_t off = ((size_t)bg*CD + cm + mtN*16 + ln)*HD + js + ks2*32 + quad*8;
                A2h[ks2][mtN] = ld8(muh + off);
                A2l[ks2][mtN] = ld8(mul_ + off);
            }
        // ---- bias loads (vectorized) ----
        float bj8[8];
        #pragma unroll
        for (int mt=0;mt<2;mt++){
            float4 bv = *(const float4*)&bias[(size_t)bg*HD + js + wave*32 + mt*16 + quad*4];
            bj8[mt*4+0]=bv.x; bj8[mt*4+1]=bv.y; bj8[mt*4+2]=bv.z; bj8[mt*4+3]=bv.w;
        }
        __builtin_amdgcn_sched_barrier(0);
        // ---- phase A: ds_read staged zT + MFMA (hi-only) ----
        f32x4 acc1[2][4];
        #pragma unroll
        for (int mt=0;mt<2;mt++)
            #pragma unroll
            for (int nt=0;nt<4;nt++) acc1[mt][nt] = z4();
        {
            s16x8 Ah[2][2];
            #pragma unroll
            for (int ks=0;ks<2;ks++)
                #pragma unroll
                for (int mt=0;mt<2;mt++){
                    int row = wave*32 + mt*16 + ln;
                    int o   = ks*64 + quad*16;
                    int ad  = row*128 + (o ^ ((row&7)<<4));
                    Ah[mt][ks] = ld8(&zs[buf][ad>>1]);
                }
            __builtin_amdgcn_s_setprio(1);
            #pragma unroll
            for (int ks=0;ks<2;ks++)
                #pragma unroll
                for (int mt=0;mt<2;mt++)
                    #pragma unroll
                    for (int nt=0;nt<4;nt++)
                        acc1[mt][nt] = mfma16(Ah[mt][ks], Bh[nt][ks], acc1[mt][nt]);
            __builtin_amdgcn_s_setprio(0);
        }
        // ---- issue staging loads for next tile ----
        const bool st = (js + 128 < HD);
        uint4 g0, g1, g2, g3;
        if (st){
            const char* srcb = (const char*)(zTh + ((size_t)bg*HD + js + 128)*CD);
            int F = wave*4096 + lane*16;
            g0 = *(const uint4*)(srcb + F);
            g1 = *(const uint4*)(srcb + F + 1024);
            g2 = *(const uint4*)(srcb + F + 2048);
            g3 = *(const uint4*)(srcb + F + 3072);
        }
        __builtin_amdgcn_sched_barrier(0);
        // ---- e compute + LDS write (buffer `buf`); racc uses the ROUNDED e ----
        #pragma unroll
        for (int mt=0;mt<2;mt++)
            #pragma unroll
            for (int nt=0;nt<4;nt++){
                u16 hh[4];
                #pragma unroll
                for (int rx=0;rx<4;rx++){
                    float e = __expf(fmaf(a, acc1[mt][nt][rx], bj8[mt*4+rx]));
                    hh[rx] = f2bf(e);
                    racc[nt] += bf2f(hh[rx]);
                }
                int row = nt*16 + ln;                        // i-local
                int c4  = wave*32 + mt*16 + quad*4;          // j-local
                int off = (row<<7) + ((((c4>>3) ^ (row&15))<<3) | (c4&7));
                *(ushort4*)&el[buf][off] = make_ushort4(hh[0],hh[1],hh[2],hh[3]);
            }
        __syncthreads();
        // ---- staging writes ----
        if (st){
            int F = wave*4096 + lane*16;
            *(uint4*)&zs[buf^1][stg_swz(F       )>>1] = g0;
            *(uint4*)&zs[buf^1][stg_swz(F + 1024)>>1] = g1;
            *(uint4*)&zs[buf^1][stg_swz(F + 2048)>>1] = g2;
            *(uint4*)&zs[buf^1][stg_swz(F + 3072)>>1] = g3;
        }
        // ---- phase B: acc2[c][i] += mu * e^T ----
        __builtin_amdgcn_s_setprio(1);
        #pragma unroll
        for (int ks2=0;ks2<4;ks2++){
            s16x8 B2h[2];
            #pragma unroll
            for (int nt2=0;nt2<2;nt2++){
                int il = in_ + nt2*16 + ln;
                int ob = (il<<7) + (((ks2*4+quad) ^ (il&15))<<3);
                B2h[nt2] = ld8(&el[buf][ob]);
            }
            #pragma unroll
            for (int mtN=0;mtN<2;mtN++)
                #pragma unroll
                for (int nt2=0;nt2<2;nt2++)
                    acc2[mtN][nt2] = mm2(A2h[ks2][mtN], A2l[ks2][mtN], B2h[nt2], acc2[mtN][nt2]);
        }
        __builtin_amdgcn_s_setprio(0);
    }
    #pragma unroll
    for (int nt=0;nt<4;nt++){
        float v = racc[nt];
        v += __shfl_xor(v,16); v += __shfl_xor(v,32);
        if (quad == 0) rl2[wave][nt*16 + ln] = v;
    }
    __syncthreads();
    #pragma unroll
    for (int nt2=0;nt2<2;nt2++){
        int il = in_ + nt2*16 + ln;
        float rinv = __builtin_amdgcn_rcpf(rl2[0][il]+rl2[1][il]+rl2[2][il]+rl2[3][il]);
        #pragma unroll
        for (int mtN=0;mtN<2;mtN++)
            #pragma unroll
            for (int rx=0;rx<4;rx++)
                out[((size_t)bg*CD + cm + mtN*16 + quad*4 + rx)*HD + i0 + il]
                    = acc2[mtN][nt2][rx] * rinv;
    }
}

extern "C" void kernel_launch(void* const* d_in, const int* in_sizes, int n_in,
                              void* d_out, int out_size, void* d_ws, size_t ws_size,
                              hipStream_t stream)
{
    (void)in_sizes; (void)n_in; (void)out_size; (void)ws_size;
    const float* q     = (const float*)d_in[0];
    const float* zeta  = (const float*)d_in[1];
    const float* alpha = (const float*)d_in[2];
    const float* mu    = (const float*)d_in[3];
    const float* beta  = (const float*)d_in[4];
    float* out = (float*)d_out;

    const size_t SZ = (size_t)NB*HD*CD;   // elements per tensor
    u16* qTh = (u16*)d_ws;
    u16* zTh = qTh + 1*SZ;
    u16* qNh = qTh + 2*SZ;
    u16* muh = qTh + 3*SZ;
    u16* mul_= qTh + 4*SZ;
    float* bias = (float*)(qTh + 5*SZ);
    float* r    = bias + (size_t)NB*HD;

    dim3 blk(256,1,1);
    int n4 = (int)(SZ/4);
    k_convert1 <<<dim3(n4/256), blk, 0, stream>>>(q,  qNh, n4);
    k_convert  <<<dim3(n4/256), blk, 0, stream>>>(mu, muh, mul_, n4);
    k_transpose1<<<dim3(HD/128, NB), blk, 0, stream>>>(q,    qTh);
    k_transpose1<<<dim3(HD/128, NB), blk, 0, stream>>>(zeta, zTh);
    k_bias     <<<dim3(HD/256, NB), blk, 0, stream>>>(mu, beta, bias);

    k_rowsum<<<dim3(HD/64, NB), blk, 0, stream>>>(qTh,zTh,bias,alpha,r);
    k_update<<<dim3(HD/64, NB), blk, 0, stream>>>(qTh,zTh,qNh,bias,alpha,r);
    k_rowsum<<<dim3(HD/64, NB), blk, 0, stream>>>(qTh,zTh,bias,alpha,r);
    k_update<<<dim3(HD/64, NB), blk, 0, stream>>>(qTh,zTh,qNh,bias,alpha,r);
    k_final <<<dim3(HD/64, NB), blk, 0, stream>>>(qTh,zTh,muh,mul_,bias,alpha,out);
}